// Round 5
// baseline (269.585 us; speedup 1.0000x reference)
//
#include <hip/hip_runtime.h>
#include <hip/hip_bf16.h>
#include <cmath>

typedef unsigned short u16;
typedef __attribute__((ext_vector_type(8))) short bf16x8;
typedef __attribute__((ext_vector_type(4))) float f32x4;
typedef __attribute__((ext_vector_type(4))) unsigned short u16x4;

// Problem constants: B=8, C=128, H=128, WIN=4, K=3, WS=64, L=16384
// Workspace layout (bytes):
#define OFF_AGG   0u          // 5 stats * 8b * 4w * 128c f32 = 81920
#define OFF_WW    81920u      // 32 f32 (unused now, kept for layout stability)
#define OFF_R     82048u      // 4*128*9 f32 = 18432
#define OFF_FSUM  100480u     // 128 f32
#define OFF_GKT   100992u     // 4*128*128 f32 = 262144
#define OFF_A     363136u     // 4*128*1152 f32 = 2359296
#define OFF_P     2722432u    // 2359296
#define OFF_M     5081728u    // (unused since k4/k5 fusion; kept for layout stability)
#define OFF_KEFF  7441024u    // [b][t][o][c] u16 = 2359296
#define OFF_XPAD  9800320u    // [b][130][130][128] u16 = 34611200  (total ~42.4 MB)

__device__ __forceinline__ u16 f2bf(float f) {
  union { float f; unsigned int u; } v; v.f = f;
  unsigned int r = v.u + 0x7FFFu + ((v.u >> 16) & 1u);
  return (u16)(r >> 16);
}

// ---------------------------------------------------------------------------
// kw: merged weight-side prep (one dispatch): R, gkT, fsum, agg-zero, and k3's A/P.
//  bid <  18 : R[w,c,t] = sum_o dc_w[w,o] * conv1_w[w*128+o, c, t]
//  bid < 274 : gkT[w][j][c] = gk_w[c][w][j]
//  bid ==274 : fsum[o] = sum_oc fusion_w[o, 512+oc]
//  bid < 279 : zero agg (replaces hipMemsetAsync)
//  else      : A/P (k3): A[w,o,m] = sum_oc fusion_w[o,w*128+oc]*cw[w,oc,m]; P with col 512+
// ---------------------------------------------------------------------------
__global__ void kw(const float* __restrict__ dc_w, const float* __restrict__ conv1_w,
                   const float* __restrict__ gk_w, const float* __restrict__ fusion_w,
                   float* __restrict__ R, float* __restrict__ gkT,
                   float* __restrict__ fsum, float* __restrict__ agg,
                   float* __restrict__ A, float* __restrict__ P) {
  const int bid = blockIdx.x, tid = threadIdx.x;
  if (bid < 18) {
    int gid = bid * 256 + tid;                  // 0..4607
    int w = gid / 1152, m = gid % 1152;
    float s = 0.f;
    for (int o = 0; o < 128; ++o)
      s += dc_w[w * 128 + o] * conv1_w[(size_t)(w * 128 + o) * 1152 + m];
    R[gid] = s;
  } else if (bid < 274) {
    int gid = (bid - 18) * 256 + tid;           // 0..65535
    int w = gid >> 14, j = (gid >> 7) & 127, c = gid & 127;
    gkT[gid] = gk_w[c * 512 + w * 128 + j];
  } else if (bid == 274) {
    if (tid < 128) {
      float s = 0.f;
      for (int oc = 0; oc < 128; ++oc) s += fusion_w[tid * 640 + 512 + oc];
      fsum[tid] = s;
    }
  } else if (bid < 279) {
    const int idx = (bid - 275) * 256 + tid;    // 0..1023, 20 floats each = 20480
    f32x4 z = {0.f, 0.f, 0.f, 0.f};
    #pragma unroll
    for (int k = 0; k < 5; ++k)
      *(f32x4*)(agg + idx * 20 + k * 4) = z;
  } else {
    int gid = (bid - 279) * 256 + tid;          // 0..147455
    int w = gid / 36864;
    int rem = gid % 36864;
    int o = rem / 288;
    int m = (rem % 288) * 4;
    const float* fw1 = fusion_w + o * 640 + w * 128;
    const float* fw4 = fusion_w + o * 640 + 512;
    const float* cw = conv1_w + (size_t)w * 128 * 1152 + m;
    float a0 = 0, a1 = 0, a2 = 0, a3 = 0, p0 = 0, p1 = 0, p2 = 0, p3 = 0;
    for (int oc = 0; oc < 128; ++oc) {
      float f1 = fw1[oc], f4 = fw4[oc];
      float4 cv = *(const float4*)(cw + (size_t)oc * 1152);
      a0 += f1 * cv.x; a1 += f1 * cv.y; a2 += f1 * cv.z; a3 += f1 * cv.w;
      p0 += f4 * cv.x; p1 += f4 * cv.y; p2 += f4 * cv.z; p3 += f4 * cv.w;
    }
    float4* Ao = (float4*)(A + (size_t)(w * 128 + o) * 1152 + m);
    float4* Po = (float4*)(P + (size_t)(w * 128 + o) * 1152 + m);
    *Ao = make_float4(a0, a1, a2, a3);
    *Po = make_float4(p0, p1, p2, p3);
  }
}

// ---------------------------------------------------------------------------
// K1 (vectorized): fp32 x -> padded bf16 image [b][130][130][128] + window aggregates.
// Block = (padded row rp, b), 256 threads: strip s = tid>>5 owns 16 pixels, cg = tid&31
// owns 4 channels. Window sums reduced via LDS, one atomic per (w,c,stat).
// agg stats: 0=T 1=rowFirst 2=rowLast 3=colFirst 4=colLast, layout [stat][b][w][c]
// ---------------------------------------------------------------------------
__global__ void k1_pad_agg(const float* __restrict__ x, u16* __restrict__ xpad,
                           float* __restrict__ agg) {
  const int rp = blockIdx.x;      // padded row 0..129
  const int b = blockIdx.y;
  const int tid = threadIdx.x;
  const size_t xpb = ((size_t)b * 130 + rp) * 16640;
  if (rp == 0 || rp == 129) {
    const bf16x8 z = {0, 0, 0, 0, 0, 0, 0, 0};
    #pragma unroll
    for (int rr = 0; rr < 8; ++rr)
      *(bf16x8*)(xpad + xpb + (size_t)(rr * 256 + tid) * 8) = z;
    if (tid < 32)
      *(bf16x8*)(xpad + xpb + (size_t)(2048 + tid) * 8) = z;
    return;
  }
  const int r = rp - 1;
  if (tid < 32) {
    *(u16x4*)(xpad + xpb + tid * 4) = (u16x4){0, 0, 0, 0};
  } else if (tid < 64) {
    *(u16x4*)(xpad + xpb + 129 * 128 + (tid - 32) * 4) = (u16x4){0, 0, 0, 0};
  }
  const int s = tid >> 5;          // pixel strip 0..7 (16 px each)
  const int cg = tid & 31;         // channel group
  const int c0 = cg * 4;
  const float* xr = x + ((size_t)b * 16384 + (size_t)r * 128) * 128;
  f32x4 sum = {0.f, 0.f, 0.f, 0.f};
  f32x4 cap = {0.f, 0.f, 0.f, 0.f};
  #pragma unroll
  for (int qi = 0; qi < 16; ++qi) {
    const int q = s * 16 + qi;
    f32x4 v = *(const f32x4*)(xr + (size_t)q * 128 + c0);
    sum += v;
    if (qi == 0 && (s == 0 || s == 4)) cap = v;   // q == 0 / 64
    if (qi == 15 && (s == 3 || s == 7)) cap = v;  // q == 63 / 127
    u16x4 st = { f2bf(v[0]), f2bf(v[1]), f2bf(v[2]), f2bf(v[3]) };
    *(u16x4*)(xpad + xpb + (size_t)(q + 1) * 128 + c0) = st;
  }
  const int i = r >> 6, rw = r & 63;
  const int abase = b * 512 + c0;
  if (s == 0) {
    #pragma unroll
    for (int k = 0; k < 4; ++k) atomicAdd(&agg[3 * 4096 + abase + (i * 2) * 128 + k], cap[k]);
  } else if (s == 4) {
    #pragma unroll
    for (int k = 0; k < 4; ++k) atomicAdd(&agg[3 * 4096 + abase + (i * 2 + 1) * 128 + k], cap[k]);
  } else if (s == 3) {
    #pragma unroll
    for (int k = 0; k < 4; ++k) atomicAdd(&agg[4 * 4096 + abase + (i * 2) * 128 + k], cap[k]);
  } else if (s == 7) {
    #pragma unroll
    for (int k = 0; k < 4; ++k) atomicAdd(&agg[4 * 4096 + abase + (i * 2 + 1) * 128 + k], cap[k]);
  }
  __shared__ f32x4 ls[8][32];
  ls[s][cg] = sum;
  __syncthreads();
  if (tid < 64) {
    const int h = tid >> 5, g = tid & 31;
    f32x4 T = ls[h * 4 + 0][g] + ls[h * 4 + 1][g] + ls[h * 4 + 2][g] + ls[h * 4 + 3][g];
    const int a = b * 512 + (i * 2 + h) * 128 + g * 4;
    #pragma unroll
    for (int k = 0; k < 4; ++k) atomicAdd(&agg[a + k], T[k]);
    if (rw == 0) {
      #pragma unroll
      for (int k = 0; k < 4; ++k) atomicAdd(&agg[4096 + a + k], T[k]);
    }
    if (rw == 63) {
      #pragma unroll
      for (int k = 0; k < 4; ++k) atomicAdd(&agg[2 * 4096 + a + k], T[k]);
    }
  }
}

// ---------------------------------------------------------------------------
// K45b: fused ww-gate (old k2, computed redundantly per block) + k4/k5 keff.
// Block = (t, o-pair). Phases:
//  (1) stage P/A slices to LDS; compute per-(b,w) S·R partial dots (8-lane groups)
//  (2) sync; tid<8 run the gelu/sigmoid MLP (one b each) while all threads do the
//      j-contraction with f32x4 gkT loads; jq-partials to LDS
//  (3) sync; combine partials + A, apply all 8 batch gates, emit keff bf16.
// ---------------------------------------------------------------------------
__global__ void k45_keff(const float* __restrict__ A, const float* __restrict__ P,
                         const float* __restrict__ gkT, const float* __restrict__ agg,
                         const float* __restrict__ x, const float* __restrict__ R,
                         const float* __restrict__ dc_b,
                         const float* __restrict__ l1_w, const float* __restrict__ l1_b,
                         const float* __restrict__ l2_w, const float* __restrict__ l2_b,
                         const float* __restrict__ fsum, const float* __restrict__ gk_b,
                         u16* __restrict__ keff) {
  const int t = blockIdx.x >> 6;          // 0..8
  const int o0 = (blockIdx.x & 63) * 2;   // o-pair base
  const int tid = threadIdx.x;
  __shared__ float pl[2][4][128];
  __shared__ float al[2][4][128];
  __shared__ float red[4][2][4][128];     // 16 KB, scalar-float to keep static indexing
  __shared__ float redw[8][4];
  __shared__ float ww_l[8][4];

  // stage P/A slices (16 KB of strided global reads; overlaps the ww phase below)
  #pragma unroll
  for (int rr = 0; rr < 4; ++rr) {
    const int idx = rr * 256 + tid;       // oi*512 + w*128 + j
    const int oi = idx >> 9, w = (idx >> 7) & 3, j = idx & 127;
    const size_t src = (size_t)(w * 128 + o0 + oi) * 1152 + j * 9 + t;
    pl[oi][w][j] = P[src];
    al[oi][w][j] = A[src];
  }

  // ww partial phase: thread -> (b = tid>>5>>2... g8 = b*4+w, l8 covers 16 c)
  {
    const int g8 = tid >> 3;              // 0..31
    const int b = g8 >> 2, w = g8 & 3;
    const int l8 = tid & 7;
    const int iw = w >> 1, jw = w & 1;
    const int r0 = iw * 64, s0 = jw * 64;
    const size_t xbase = (size_t)b * 16384 * 128;
    float partial = 0.f;
    for (int k = 0; k < 16; ++k) {
      const int c = l8 * 16 + k;
      const int ai = b * 512 + w * 128 + c;
      float T  = agg[ai];
      float rF = agg[4096 + ai];
      float rL = agg[2 * 4096 + ai];
      float cF = agg[3 * 4096 + ai];
      float cL = agg[4 * 4096 + ai];
      float c00 = x[xbase + ((size_t)(r0 + 0)  * 128 + (s0 + 0))  * 128 + c];
      float c0L = x[xbase + ((size_t)(r0 + 0)  * 128 + (s0 + 63)) * 128 + c];
      float cL0 = x[xbase + ((size_t)(r0 + 63) * 128 + (s0 + 0))  * 128 + c];
      float cLL = x[xbase + ((size_t)(r0 + 63) * 128 + (s0 + 63)) * 128 + c];
      float S[9];
      S[0] = T - rL - cL + cLL;
      S[1] = T - rL;
      S[2] = T - rL - cF + cL0;
      S[3] = T - cL;
      S[4] = T;
      S[5] = T - cF;
      S[6] = T - rF - cL + c0L;
      S[7] = T - rF;
      S[8] = T - rF - cF + c00;
      const float* Rp = R + (w * 128 + c) * 9;
      #pragma unroll
      for (int tt = 0; tt < 9; ++tt) partial += S[tt] * Rp[tt];
    }
    #pragma unroll
    for (int off = 4; off > 0; off >>= 1) partial += __shfl_xor(partial, off, 8);
    if (l8 == 0) redw[b][w] = partial;
  }
  __syncthreads();

  // MLP on 8 threads (one batch each); other threads proceed to the contraction
  if (tid < 8) {
    const int b = tid;
    float ww0[4];
    #pragma unroll
    for (int w2 = 0; w2 < 4; ++w2) ww0[w2] = redw[b][w2] * (1.f / 4096.f) + dc_b[w2];
    float h1[16];
    for (int i2 = 0; i2 < 16; ++i2) {
      float s = l1_b[i2];
      #pragma unroll
      for (int w2 = 0; w2 < 4; ++w2) s += l1_w[i2 * 4 + w2] * ww0[w2];
      h1[i2] = 0.5f * s * (1.f + erff(s * 0.70710678118654752f));
    }
    #pragma unroll
    for (int w2 = 0; w2 < 4; ++w2) {
      float s = l2_b[w2];
      for (int i2 = 0; i2 < 16; ++i2) s += l2_w[w2 * 16 + i2] * h1[i2];
      ww_l[b][w2] = 1.f / (1.f + expf(-s));
    }
  }

  // j-contraction: thread -> (cq = tid&31, oi = bit5, jq = tid>>6); f32x4 gkT loads
  {
    const int cq = tid & 31;
    const int oi = (tid >> 5) & 1;
    const int jq = tid >> 6;
    f32x4 acc0 = {0,0,0,0}, acc1 = {0,0,0,0}, acc2 = {0,0,0,0}, acc3 = {0,0,0,0};
    const float* gbase = gkT + cq * 4;
    for (int j5 = 0; j5 < 32; ++j5) {
      const int j = jq * 32 + j5;
      f32x4 g0 = *(const f32x4*)(gbase + 0 * 16384 + j * 128);
      f32x4 g1 = *(const f32x4*)(gbase + 1 * 16384 + j * 128);
      f32x4 g2 = *(const f32x4*)(gbase + 2 * 16384 + j * 128);
      f32x4 g3 = *(const f32x4*)(gbase + 3 * 16384 + j * 128);
      acc0 += pl[oi][0][j] * g0;
      acc1 += pl[oi][1][j] * g1;
      acc2 += pl[oi][2][j] * g2;
      acc3 += pl[oi][3][j] * g3;
    }
    *(f32x4*)&red[jq][oi][0][cq * 4] = acc0;
    *(f32x4*)&red[jq][oi][1][cq * 4] = acc1;
    *(f32x4*)&red[jq][oi][2][cq * 4] = acc2;
    *(f32x4*)&red[jq][oi][3][cq * 4] = acc3;
  }
  __syncthreads();

  // epilogue: combine + gates + store
  {
    const int oi2 = tid >> 7, c2 = tid & 127;
    float m[4];
    #pragma unroll
    for (int w = 0; w < 4; ++w)
      m[w] = red[0][oi2][w][c2] + red[1][oi2][w][c2] + red[2][oi2][w][c2]
           + red[3][oi2][w][c2] + al[oi2][w][c2];
    const float base = fsum[o0 + oi2] * gk_b[c2];
    #pragma unroll
    for (int b = 0; b < 8; ++b) {
      float r = base;
      #pragma unroll
      for (int w = 0; w < 4; ++w) r += ww_l[b][w] * m[w];
      keff[(size_t)b * 147456 + (size_t)t * 16384 + (o0 + oi2) * 128 + c2] = f2bf(r);
    }
  }
}

// ---------------------------------------------------------------------------
// K6: per-batch 3x3 C->C conv as 9 accumulated bf16 MFMA GEMMs. (unchanged control)
// Block = (b, image row p): out tile 128 pixels x 128 o; 4 waves in 2x2 (64m x 64n each).
//  - A: one padded image row staged once per dh-group via global_load_lds DMA with
//       PRE-SWIZZLED GLOBAL addresses (LDS dest linear).
//  - W: 32 KB/tap, single-buffered, reg-staged (loads overlap compute, write after barrier).
// Reads of both use off = lin ^ ((row&7)<<3). LDS total 66,560 B -> 2 blocks/CU.
// ---------------------------------------------------------------------------
__global__ __launch_bounds__(256, 2) void k6_conv(
    const u16* __restrict__ xpad, const u16* __restrict__ keff,
    const float* __restrict__ fusion_b, float* __restrict__ out) {
  __shared__ __align__(16) u16 alds[130 * 128];   // 33,280 B
  __shared__ __align__(16) u16 apad[256];         // 512 B guard for masked DMA tail
  __shared__ __align__(16) u16 wlds[128 * 128];   // 32,768 B
  const int tid = threadIdx.x;
  const int blk = blockIdx.x;
  const int b = blk & 7;            // XCD affinity: batch <-> XCD
  const int p = blk >> 3;
  const int wid = tid >> 6;
  const int lane = tid & 63;
  const int wm = (wid & 1) * 64;
  const int wn = (wid >> 1) * 64;
  const int quad = lane >> 4;
  const int l16 = lane & 15;

  f32x4 acc[4][4];
  #pragma unroll
  for (int i = 0; i < 4; ++i)
    #pragma unroll
    for (int j = 0; j < 4; ++j)
      acc[i][j] = (f32x4){0.f, 0.f, 0.f, 0.f};

  const u16* kb = keff + (size_t)b * 147456;
  const u16* xb = xpad + (size_t)b * 130 * 16640;
  bf16x8 streg[8];
  (void)apad;

  auto stage_W_load = [&](int tap) {
    const u16* src = kb + tap * 16384;
    #pragma unroll
    for (int it = 0; it < 8; ++it) {
      const int chunk = it * 256 + tid;
      const int gs = chunk ^ ((chunk >> 4) & 7);
      streg[it] = *(const bf16x8*)(src + gs * 8);
    }
  };
  auto stage_W_write = [&]() {
    #pragma unroll
    for (int it = 0; it < 8; ++it)
      *(bf16x8*)(wlds + (it * 256 + tid) * 8) = streg[it];
  };
  auto stage_A_dma = [&](int prow) {
    const u16* src = xb + (size_t)prow * 16640;
    #pragma unroll
    for (int r = 0; r < 8; ++r) {
      const int chunk = (wid * 8 + r) * 64 + lane;
      const int gs = chunk ^ ((chunk >> 4) & 7);
      __builtin_amdgcn_global_load_lds(
          (const __attribute__((address_space(1))) unsigned int*)(src + (size_t)gs * 8),
          (__attribute__((address_space(3))) unsigned int*)(alds + (wid * 8 + r) * 512),
          16, 0, 0);
    }
    if (tid < 32) {
      const int chunk = 2048 + tid;
      const int gs = chunk ^ ((chunk >> 4) & 7);
      __builtin_amdgcn_global_load_lds(
          (const __attribute__((address_space(1))) unsigned int*)(src + (size_t)gs * 8),
          (__attribute__((address_space(3))) unsigned int*)(alds + 2048 * 8),
          16, 0, 0);
    }
  };

  stage_W_load(0);
  stage_A_dma(p);
  stage_W_write();
  __syncthreads();   // drains vmcnt -> DMA complete, W visible

  for (int tap = 0; tap < 9; ++tap) {
    if (tap < 8) stage_W_load(tap + 1);         // global->reg, overlaps MFMA
    const int dw = tap % 3 - 1;
    const int pixoff = 1 + dw;
    #pragma unroll
    for (int kc = 0; kc < 4; ++kc) {
      const int c0 = kc * 32 + quad * 8;
      bf16x8 a[4], bb[4];
      #pragma unroll
      for (int i = 0; i < 4; ++i) {
        const int pix = pixoff + wm + i * 16 + l16;
        const int off = (pix * 128 + c0) ^ ((pix & 7) << 3);
        a[i] = *(const bf16x8*)(alds + off);
      }
      #pragma unroll
      for (int j = 0; j < 4; ++j) {
        const int row = wn + j * 16 + l16;
        const int off = (row * 128 + c0) ^ ((row & 7) << 3);
        bb[j] = *(const bf16x8*)(wlds + off);
      }
      #pragma unroll
      for (int i = 0; i < 4; ++i)
        #pragma unroll
        for (int j = 0; j < 4; ++j)
          acc[i][j] = __builtin_amdgcn_mfma_f32_16x16x32_bf16(a[i], bb[j], acc[i][j], 0, 0, 0);
    }
    __syncthreads();                            // all waves done reading alds/wlds
    if (tap < 8) {
      stage_W_write();                          // vmcnt waits streg, then ds_write
      if (tap % 3 == 2) stage_A_dma(p + (tap + 1) / 3);  // next dh row
      __syncthreads();                          // drains vmcnt -> DMA + writes visible
    }
  }

  float fb[4];
  #pragma unroll
  for (int j = 0; j < 4; ++j) fb[j] = fusion_b[wn + j * 16 + l16];
  float* outb = out + ((size_t)b * 16384 + (size_t)p * 128) * 128;
  #pragma unroll
  for (int i = 0; i < 4; ++i)
    #pragma unroll
    for (int r = 0; r < 4; ++r) {
      const int m = wm + i * 16 + quad * 4 + r;
      #pragma unroll
      for (int j = 0; j < 4; ++j)
        outb[(size_t)m * 128 + (wn + j * 16 + l16)] = acc[i][j][r] + fb[j];
    }
}

extern "C" void kernel_launch(void* const* d_in, const int* in_sizes, int n_in,
                              void* d_out, int out_size, void* d_ws, size_t ws_size,
                              hipStream_t stream) {
  const float* x        = (const float*)d_in[0];
  const float* conv1_w  = (const float*)d_in[1];
  const float* dc_w     = (const float*)d_in[2];
  const float* dc_b     = (const float*)d_in[3];
  const float* l1_w     = (const float*)d_in[4];
  const float* l1_b     = (const float*)d_in[5];
  const float* l2_w     = (const float*)d_in[6];
  const float* l2_b     = (const float*)d_in[7];
  const float* gk_w     = (const float*)d_in[8];
  const float* gk_b     = (const float*)d_in[9];
  const float* fusion_w = (const float*)d_in[10];
  const float* fusion_b = (const float*)d_in[11];
  float* out = (float*)d_out;
  char* ws = (char*)d_ws;

  float* agg  = (float*)(ws + OFF_AGG);
  float* R    = (float*)(ws + OFF_R);
  float* fsum = (float*)(ws + OFF_FSUM);
  float* gkT  = (float*)(ws + OFF_GKT);
  float* A    = (float*)(ws + OFF_A);
  float* P    = (float*)(ws + OFF_P);
  u16* keff   = (u16*)(ws + OFF_KEFF);
  u16* xpad   = (u16*)(ws + OFF_XPAD);

  // 4 dispatches total (was 7): weight-side prep+zero, x-side pad+agg, keff, conv.
  kw<<<855, 256, 0, stream>>>(dc_w, conv1_w, gk_w, fusion_w, R, gkT, fsum, agg, A, P);
  k1_pad_agg<<<dim3(130, 8), 256, 0, stream>>>(x, xpad, agg);
  k45_keff<<<576, 256, 0, stream>>>(A, P, gkT, agg, x, R, dc_b,
                                    l1_w, l1_b, l2_w, l2_b, fsum, gk_b, keff);
  k6_conv<<<1024, 256, 0, stream>>>(xpad, keff, fusion_b, out);
}

// Round 6
// 226.664 us; speedup vs baseline: 1.1894x; 1.1894x over previous
//
#include <hip/hip_runtime.h>
#include <hip/hip_bf16.h>
#include <cmath>

typedef unsigned short u16;
typedef __attribute__((ext_vector_type(8))) short bf16x8;
typedef __attribute__((ext_vector_type(4))) float f32x4;
typedef __attribute__((ext_vector_type(4))) unsigned short u16x4;

// Problem constants: B=8, C=128, H=128, WIN=4, K=3, WS=64, L=16384
// Workspace layout (bytes):
#define OFF_AGG   0u          // 5 stats * 8b * 4w * 128c f32 = 81920
#define OFF_WW    81920u      // 32 f32
#define OFF_R     82048u      // 4*128*9 f32 = 18432
#define OFF_FSUM  100480u     // 128 f32
#define OFF_GKT   100992u     // 4*128*128 f32 = 262144
#define OFF_A     363136u     // 4*128*1152 f32 = 2359296
#define OFF_P     2722432u    // 2359296
#define OFF_M     5081728u    // (unused; kept for layout stability)
#define OFF_KEFF  7441024u    // [b][t][o][c] u16 = 2359296
#define OFF_XPAD  9800320u    // [b][130][130][128] u16 = 34611200  (total ~42.4 MB)

__device__ __forceinline__ u16 f2bf(float f) {
  union { float f; unsigned int u; } v; v.f = f;
  unsigned int r = v.u + 0x7FFFu + ((v.u >> 16) & 1u);
  return (u16)(r >> 16);
}

// ---------------------------------------------------------------------------
// kw: merged weight-side prep (one dispatch): R, gkT, fsum, agg-zero, and A/P.
// ---------------------------------------------------------------------------
__global__ void kw(const float* __restrict__ dc_w, const float* __restrict__ conv1_w,
                   const float* __restrict__ gk_w, const float* __restrict__ fusion_w,
                   float* __restrict__ R, float* __restrict__ gkT,
                   float* __restrict__ fsum, float* __restrict__ agg,
                   float* __restrict__ A, float* __restrict__ P) {
  const int bid = blockIdx.x, tid = threadIdx.x;
  if (bid < 18) {
    int gid = bid * 256 + tid;                  // 0..4607
    int w = gid / 1152, m = gid % 1152;
    float s = 0.f;
    for (int o = 0; o < 128; ++o)
      s += dc_w[w * 128 + o] * conv1_w[(size_t)(w * 128 + o) * 1152 + m];
    R[gid] = s;
  } else if (bid < 274) {
    int gid = (bid - 18) * 256 + tid;           // 0..65535
    int w = gid >> 14, j = (gid >> 7) & 127, c = gid & 127;
    gkT[gid] = gk_w[c * 512 + w * 128 + j];
  } else if (bid == 274) {
    if (tid < 128) {
      float s = 0.f;
      for (int oc = 0; oc < 128; ++oc) s += fusion_w[tid * 640 + 512 + oc];
      fsum[tid] = s;
    }
  } else if (bid < 279) {
    const int idx = (bid - 275) * 256 + tid;    // 0..1023, 20 floats each = 20480
    f32x4 z = {0.f, 0.f, 0.f, 0.f};
    #pragma unroll
    for (int k = 0; k < 5; ++k)
      *(f32x4*)(agg + idx * 20 + k * 4) = z;
  } else {
    int gid = (bid - 279) * 256 + tid;          // 0..147455
    int w = gid / 36864;
    int rem = gid % 36864;
    int o = rem / 288;
    int m = (rem % 288) * 4;
    const float* fw1 = fusion_w + o * 640 + w * 128;
    const float* fw4 = fusion_w + o * 640 + 512;
    const float* cw = conv1_w + (size_t)w * 128 * 1152 + m;
    float a0 = 0, a1 = 0, a2 = 0, a3 = 0, p0 = 0, p1 = 0, p2 = 0, p3 = 0;
    for (int oc = 0; oc < 128; ++oc) {
      float f1 = fw1[oc], f4 = fw4[oc];
      float4 cv = *(const float4*)(cw + (size_t)oc * 1152);
      a0 += f1 * cv.x; a1 += f1 * cv.y; a2 += f1 * cv.z; a3 += f1 * cv.w;
      p0 += f4 * cv.x; p1 += f4 * cv.y; p2 += f4 * cv.z; p3 += f4 * cv.w;
    }
    float4* Ao = (float4*)(A + (size_t)(w * 128 + o) * 1152 + m);
    float4* Po = (float4*)(P + (size_t)(w * 128 + o) * 1152 + m);
    *Ao = make_float4(a0, a1, a2, a3);
    *Po = make_float4(p0, p1, p2, p3);
  }
}

// ---------------------------------------------------------------------------
// K1 (vectorized): fp32 x -> padded bf16 image + window aggregates.
// ---------------------------------------------------------------------------
__global__ void k1_pad_agg(const float* __restrict__ x, u16* __restrict__ xpad,
                           float* __restrict__ agg) {
  const int rp = blockIdx.x;      // padded row 0..129
  const int b = blockIdx.y;
  const int tid = threadIdx.x;
  const size_t xpb = ((size_t)b * 130 + rp) * 16640;
  if (rp == 0 || rp == 129) {
    const bf16x8 z = {0, 0, 0, 0, 0, 0, 0, 0};
    #pragma unroll
    for (int rr = 0; rr < 8; ++rr)
      *(bf16x8*)(xpad + xpb + (size_t)(rr * 256 + tid) * 8) = z;
    if (tid < 32)
      *(bf16x8*)(xpad + xpb + (size_t)(2048 + tid) * 8) = z;
    return;
  }
  const int r = rp - 1;
  if (tid < 32) {
    *(u16x4*)(xpad + xpb + tid * 4) = (u16x4){0, 0, 0, 0};
  } else if (tid < 64) {
    *(u16x4*)(xpad + xpb + 129 * 128 + (tid - 32) * 4) = (u16x4){0, 0, 0, 0};
  }
  const int s = tid >> 5;          // pixel strip 0..7 (16 px each)
  const int cg = tid & 31;         // channel group
  const int c0 = cg * 4;
  const float* xr = x + ((size_t)b * 16384 + (size_t)r * 128) * 128;
  f32x4 sum = {0.f, 0.f, 0.f, 0.f};
  f32x4 cap = {0.f, 0.f, 0.f, 0.f};
  #pragma unroll
  for (int qi = 0; qi < 16; ++qi) {
    const int q = s * 16 + qi;
    f32x4 v = *(const f32x4*)(xr + (size_t)q * 128 + c0);
    sum += v;
    if (qi == 0 && (s == 0 || s == 4)) cap = v;   // q == 0 / 64
    if (qi == 15 && (s == 3 || s == 7)) cap = v;  // q == 63 / 127
    u16x4 st = { f2bf(v[0]), f2bf(v[1]), f2bf(v[2]), f2bf(v[3]) };
    *(u16x4*)(xpad + xpb + (size_t)(q + 1) * 128 + c0) = st;
  }
  const int i = r >> 6, rw = r & 63;
  const int abase = b * 512 + c0;
  if (s == 0) {
    #pragma unroll
    for (int k = 0; k < 4; ++k) atomicAdd(&agg[3 * 4096 + abase + (i * 2) * 128 + k], cap[k]);
  } else if (s == 4) {
    #pragma unroll
    for (int k = 0; k < 4; ++k) atomicAdd(&agg[3 * 4096 + abase + (i * 2 + 1) * 128 + k], cap[k]);
  } else if (s == 3) {
    #pragma unroll
    for (int k = 0; k < 4; ++k) atomicAdd(&agg[4 * 4096 + abase + (i * 2) * 128 + k], cap[k]);
  } else if (s == 7) {
    #pragma unroll
    for (int k = 0; k < 4; ++k) atomicAdd(&agg[4 * 4096 + abase + (i * 2 + 1) * 128 + k], cap[k]);
  }
  __shared__ f32x4 ls[8][32];
  ls[s][cg] = sum;
  __syncthreads();
  if (tid < 64) {
    const int h = tid >> 5, g = tid & 31;
    f32x4 T = ls[h * 4 + 0][g] + ls[h * 4 + 1][g] + ls[h * 4 + 2][g] + ls[h * 4 + 3][g];
    const int a = b * 512 + (i * 2 + h) * 128 + g * 4;
    #pragma unroll
    for (int k = 0; k < 4; ++k) atomicAdd(&agg[a + k], T[k]);
    if (rw == 0) {
      #pragma unroll
      for (int k = 0; k < 4; ++k) atomicAdd(&agg[4096 + a + k], T[k]);
    }
    if (rw == 63) {
      #pragma unroll
      for (int k = 0; k < 4; ++k) atomicAdd(&agg[2 * 4096 + a + k], T[k]);
    }
  }
}

// ---------------------------------------------------------------------------
// K2: per-batch SE gate ww[b][w] (restored standalone dispatch — fusing it into
// the 576-block k45 cost +50 µs of redundant scattered loads; round-5 lesson).
// ---------------------------------------------------------------------------
__global__ void k2_ww(const float* __restrict__ x, const float* __restrict__ agg,
                      const float* __restrict__ R, const float* __restrict__ dc_b,
                      const float* __restrict__ l1_w, const float* __restrict__ l1_b,
                      const float* __restrict__ l2_w, const float* __restrict__ l2_b,
                      float* __restrict__ ww) {
  const int b = blockIdx.x;
  const int tid = threadIdx.x;
  const int w = tid >> 6, lane = tid & 63;
  __shared__ float red[4];
  float partial = 0.f;
  const int i = w >> 1, j = w & 1;
  const int r0 = i * 64, s0 = j * 64;
  const size_t base = (size_t)b * 16384 * 128;
  #pragma unroll
  for (int k = 0; k < 2; ++k) {
    const int c = lane * 2 + k;
    const int ai = b * 512 + w * 128 + c;
    float T  = agg[ai];
    float rF = agg[4096 + ai];
    float rL = agg[2 * 4096 + ai];
    float cF = agg[3 * 4096 + ai];
    float cL = agg[4 * 4096 + ai];
    float c00 = x[base + ((size_t)(r0 + 0)  * 128 + (s0 + 0))  * 128 + c];
    float c0L = x[base + ((size_t)(r0 + 0)  * 128 + (s0 + 63)) * 128 + c];
    float cL0 = x[base + ((size_t)(r0 + 63) * 128 + (s0 + 0))  * 128 + c];
    float cLL = x[base + ((size_t)(r0 + 63) * 128 + (s0 + 63)) * 128 + c];
    float S[9];
    S[0] = T - rL - cL + cLL;
    S[1] = T - rL;
    S[2] = T - rL - cF + cL0;
    S[3] = T - cL;
    S[4] = T;
    S[5] = T - cF;
    S[6] = T - rF - cL + c0L;
    S[7] = T - rF;
    S[8] = T - rF - cF + c00;
    const float* Rp = R + (w * 128 + c) * 9;
    #pragma unroll
    for (int t = 0; t < 9; ++t) partial += S[t] * Rp[t];
  }
  for (int off = 32; off > 0; off >>= 1) partial += __shfl_xor(partial, off, 64);
  if (lane == 0) red[w] = partial;
  __syncthreads();
  if (tid == 0) {
    float ww0[4];
    #pragma unroll
    for (int w2 = 0; w2 < 4; ++w2) ww0[w2] = red[w2] * (1.f / 4096.f) + dc_b[w2];
    float h1[16];
    for (int i2 = 0; i2 < 16; ++i2) {
      float s = l1_b[i2];
      #pragma unroll
      for (int w2 = 0; w2 < 4; ++w2) s += l1_w[i2 * 4 + w2] * ww0[w2];
      h1[i2] = 0.5f * s * (1.f + erff(s * 0.70710678118654752f));
    }
    for (int w2 = 0; w2 < 4; ++w2) {
      float s = l2_b[w2];
      for (int i2 = 0; i2 < 16; ++i2) s += l2_w[w2 * 16 + i2] * h1[i2];
      ww[b * 4 + w2] = 1.f / (1.f + expf(-s));
    }
  }
}

// ---------------------------------------------------------------------------
// K45: fused k4+k5 (round-4 proven body): reads precomputed ww.
// keff[b,t,o,c] = f2bf( sum_w ww[b,w]*(A[w,o,c*9+t] + sum_j P[w,o,j*9+t]*gkT[w,j,c])
//                       + fsum[o]*gk_b[c] )
// ---------------------------------------------------------------------------
__global__ void k45_keff(const float* __restrict__ A, const float* __restrict__ P,
                         const float* __restrict__ gkT, const float* __restrict__ ww,
                         const float* __restrict__ fsum, const float* __restrict__ gk_b,
                         u16* __restrict__ keff) {
  const int t = blockIdx.x >> 6;          // 0..8
  const int o0 = (blockIdx.x & 63) * 2;   // o-pair base
  const int tid = threadIdx.x;
  __shared__ float pl[2][4][128];
  __shared__ float al[2][4][128];
  __shared__ float red[2][2][4][128];
  #pragma unroll
  for (int rr = 0; rr < 4; ++rr) {
    const int idx = rr * 256 + tid;       // oi*512 + w*128 + j
    const int oi = idx >> 9, w = (idx >> 7) & 3, j = idx & 127;
    const size_t src = (size_t)(w * 128 + o0 + oi) * 1152 + j * 9 + t;
    pl[oi][w][j] = P[src];
    al[oi][w][j] = A[src];
  }
  __syncthreads();
  const int c = tid & 127, jh = tid >> 7;
  float acc[2][4];
  #pragma unroll
  for (int oi = 0; oi < 2; ++oi)
    #pragma unroll
    for (int w = 0; w < 4; ++w) acc[oi][w] = 0.f;
  const float* g = gkT + c;
  #pragma unroll 4
  for (int j = jh * 64; j < jh * 64 + 64; ++j) {
    const float g0 = g[0 * 16384 + j * 128];
    const float g1 = g[1 * 16384 + j * 128];
    const float g2 = g[2 * 16384 + j * 128];
    const float g3 = g[3 * 16384 + j * 128];
    #pragma unroll
    for (int oi = 0; oi < 2; ++oi) {
      acc[oi][0] += pl[oi][0][j] * g0;
      acc[oi][1] += pl[oi][1][j] * g1;
      acc[oi][2] += pl[oi][2][j] * g2;
      acc[oi][3] += pl[oi][3][j] * g3;
    }
  }
  #pragma unroll
  for (int oi = 0; oi < 2; ++oi)
    #pragma unroll
    for (int w = 0; w < 4; ++w) red[jh][oi][w][c] = acc[oi][w];
  __syncthreads();
  const int oi2 = tid >> 7, c2 = tid & 127;
  float m[4];
  #pragma unroll
  for (int w = 0; w < 4; ++w)
    m[w] = red[0][oi2][w][c2] + red[1][oi2][w][c2] + al[oi2][w][c2];
  const float base = fsum[o0 + oi2] * gk_b[c2];
  #pragma unroll
  for (int b = 0; b < 8; ++b) {
    float r = base;
    #pragma unroll
    for (int w = 0; w < 4; ++w) r += ww[b * 4 + w] * m[w];
    keff[(size_t)b * 147456 + (size_t)t * 16384 + (o0 + oi2) * 128 + c2] = f2bf(r);
  }
}

// ---------------------------------------------------------------------------
// K6: per-batch 3x3 C->C conv as 9 accumulated bf16 MFMA GEMMs.
// Only change this round: A-DMA issued BEFORE the W ds_writes in the same
// barrier interval (head start before the vmcnt-draining barrier).
// ---------------------------------------------------------------------------
__global__ __launch_bounds__(256, 2) void k6_conv(
    const u16* __restrict__ xpad, const u16* __restrict__ keff,
    const float* __restrict__ fusion_b, float* __restrict__ out) {
  __shared__ __align__(16) u16 alds[130 * 128];   // 33,280 B
  __shared__ __align__(16) u16 apad[256];         // 512 B guard for masked DMA tail
  __shared__ __align__(16) u16 wlds[128 * 128];   // 32,768 B
  const int tid = threadIdx.x;
  const int blk = blockIdx.x;
  const int b = blk & 7;            // XCD affinity: batch <-> XCD
  const int p = blk >> 3;
  const int wid = tid >> 6;
  const int lane = tid & 63;
  const int wm = (wid & 1) * 64;
  const int wn = (wid >> 1) * 64;
  const int quad = lane >> 4;
  const int l16 = lane & 15;

  f32x4 acc[4][4];
  #pragma unroll
  for (int i = 0; i < 4; ++i)
    #pragma unroll
    for (int j = 0; j < 4; ++j)
      acc[i][j] = (f32x4){0.f, 0.f, 0.f, 0.f};

  const u16* kb = keff + (size_t)b * 147456;
  const u16* xb = xpad + (size_t)b * 130 * 16640;
  bf16x8 streg[8];
  (void)apad;

  auto stage_W_load = [&](int tap) {
    const u16* src = kb + tap * 16384;
    #pragma unroll
    for (int it = 0; it < 8; ++it) {
      const int chunk = it * 256 + tid;
      const int gs = chunk ^ ((chunk >> 4) & 7);
      streg[it] = *(const bf16x8*)(src + gs * 8);
    }
  };
  auto stage_W_write = [&]() {
    #pragma unroll
    for (int it = 0; it < 8; ++it)
      *(bf16x8*)(wlds + (it * 256 + tid) * 8) = streg[it];
  };
  auto stage_A_dma = [&](int prow) {
    const u16* src = xb + (size_t)prow * 16640;
    #pragma unroll
    for (int r = 0; r < 8; ++r) {
      const int chunk = (wid * 8 + r) * 64 + lane;
      const int gs = chunk ^ ((chunk >> 4) & 7);
      __builtin_amdgcn_global_load_lds(
          (const __attribute__((address_space(1))) unsigned int*)(src + (size_t)gs * 8),
          (__attribute__((address_space(3))) unsigned int*)(alds + (wid * 8 + r) * 512),
          16, 0, 0);
    }
    if (tid < 32) {
      const int chunk = 2048 + tid;
      const int gs = chunk ^ ((chunk >> 4) & 7);
      __builtin_amdgcn_global_load_lds(
          (const __attribute__((address_space(1))) unsigned int*)(src + (size_t)gs * 8),
          (__attribute__((address_space(3))) unsigned int*)(alds + 2048 * 8),
          16, 0, 0);
    }
  };

  stage_W_load(0);
  stage_A_dma(p);
  stage_W_write();
  __syncthreads();   // drains vmcnt -> DMA complete, W visible

  for (int tap = 0; tap < 9; ++tap) {
    if (tap < 8) stage_W_load(tap + 1);         // global->reg, overlaps MFMA
    const int dw = tap % 3 - 1;
    const int pixoff = 1 + dw;
    #pragma unroll
    for (int kc = 0; kc < 4; ++kc) {
      const int c0 = kc * 32 + quad * 8;
      bf16x8 a[4], bb[4];
      #pragma unroll
      for (int i = 0; i < 4; ++i) {
        const int pix = pixoff + wm + i * 16 + l16;
        const int off = (pix * 128 + c0) ^ ((pix & 7) << 3);
        a[i] = *(const bf16x8*)(alds + off);
      }
      #pragma unroll
      for (int j = 0; j < 4; ++j) {
        const int row = wn + j * 16 + l16;
        const int off = (row * 128 + c0) ^ ((row & 7) << 3);
        bb[j] = *(const bf16x8*)(wlds + off);
      }
      #pragma unroll
      for (int i = 0; i < 4; ++i)
        #pragma unroll
        for (int j = 0; j < 4; ++j)
          acc[i][j] = __builtin_amdgcn_mfma_f32_16x16x32_bf16(a[i], bb[j], acc[i][j], 0, 0, 0);
    }
    __syncthreads();                            // all waves done reading alds/wlds
    if (tap < 8) {
      if (tap % 3 == 2) stage_A_dma(p + (tap + 1) / 3);  // issue DMA first (head start)
      stage_W_write();                          // vmcnt waits streg, then ds_write
      __syncthreads();                          // drains vmcnt -> DMA + writes visible
    }
  }

  float fb[4];
  #pragma unroll
  for (int j = 0; j < 4; ++j) fb[j] = fusion_b[wn + j * 16 + l16];
  float* outb = out + ((size_t)b * 16384 + (size_t)p * 128) * 128;
  #pragma unroll
  for (int i = 0; i < 4; ++i)
    #pragma unroll
    for (int r = 0; r < 4; ++r) {
      const int m = wm + i * 16 + quad * 4 + r;
      #pragma unroll
      for (int j = 0; j < 4; ++j)
        outb[(size_t)m * 128 + (wn + j * 16 + l16)] = acc[i][j][r] + fb[j];
    }
}

extern "C" void kernel_launch(void* const* d_in, const int* in_sizes, int n_in,
                              void* d_out, int out_size, void* d_ws, size_t ws_size,
                              hipStream_t stream) {
  const float* x        = (const float*)d_in[0];
  const float* conv1_w  = (const float*)d_in[1];
  const float* dc_w     = (const float*)d_in[2];
  const float* dc_b     = (const float*)d_in[3];
  const float* l1_w     = (const float*)d_in[4];
  const float* l1_b     = (const float*)d_in[5];
  const float* l2_w     = (const float*)d_in[6];
  const float* l2_b     = (const float*)d_in[7];
  const float* gk_w     = (const float*)d_in[8];
  const float* gk_b     = (const float*)d_in[9];
  const float* fusion_w = (const float*)d_in[10];
  const float* fusion_b = (const float*)d_in[11];
  float* out = (float*)d_out;
  char* ws = (char*)d_ws;

  float* agg  = (float*)(ws + OFF_AGG);
  float* wwp  = (float*)(ws + OFF_WW);
  float* R    = (float*)(ws + OFF_R);
  float* fsum = (float*)(ws + OFF_FSUM);
  float* gkT  = (float*)(ws + OFF_GKT);
  float* A    = (float*)(ws + OFF_A);
  float* P    = (float*)(ws + OFF_P);
  u16* keff   = (u16*)(ws + OFF_KEFF);
  u16* xpad   = (u16*)(ws + OFF_XPAD);

  // 5 dispatches: weight-side prep+zero, x-side pad+agg, tiny ww, keff, conv.
  kw<<<855, 256, 0, stream>>>(dc_w, conv1_w, gk_w, fusion_w, R, gkT, fsum, agg, A, P);
  k1_pad_agg<<<dim3(130, 8), 256, 0, stream>>>(x, xpad, agg);
  k2_ww<<<8, 256, 0, stream>>>(x, agg, R, dc_b, l1_w, l1_b, l2_w, l2_b, wwp);
  k45_keff<<<576, 256, 0, stream>>>(A, P, gkT, wwp, fsum, gk_b, keff);
  k6_conv<<<1024, 256, 0, stream>>>(xpad, keff, fusion_b, out);
}

// Round 7
// 218.979 us; speedup vs baseline: 1.2311x; 1.0351x over previous
//
#include <hip/hip_runtime.h>
#include <hip/hip_bf16.h>
#include <cmath>

typedef unsigned short u16;
typedef __attribute__((ext_vector_type(8))) short bf16x8;
typedef __attribute__((ext_vector_type(4))) float f32x4;
typedef __attribute__((ext_vector_type(4))) unsigned short u16x4;

// Problem constants: B=8, C=128, H=128, WIN=4, K=3, WS=64, L=16384
// Workspace layout (bytes):
#define OFF_AGG   0u          // (free)
#define OFF_WW    81920u      // 32 f32
#define OFF_R     82048u      // 4*128*9 f32 = 18432
#define OFF_FSUM  100480u     // 128 f32
#define OFF_GKT   100992u     // 4*128*128 f32 = 262144
#define OFF_A     363136u     // 4*128*1152 f32 = 2359296
#define OFF_P     2722432u    // 2359296
#define OFF_M     5081728u    // reused: rowT (1 MB) + colF (1 MB)
#define OFF_KEFF  7441024u    // [b][t][o][c] u16 = 2359296; first 1 MB doubles as colL (D1->D2)
#define OFF_XPAD  9800320u    // [b][130][130][128] u16 = 34611200  (total ~42.4 MB)

__device__ __forceinline__ u16 f2bf(float f) {
  union { float f; unsigned int u; } v; v.f = f;
  unsigned int r = v.u + 0x7FFFu + ((v.u >> 16) & 1u);
  return (u16)(r >> 16);
}

// ---------------------------------------------------------------------------
// kd1: merged weight-side prep AND x-side pad/stats in ONE dispatch (no deps:
// outputs disjoint, no ordering). Atomic-free stats: per-row partials stored
// with plain coalesced f32x4 stores (old per-80KB-agg device atomics from all
// 8 XCDs were k1's bottleneck).
//  bid <  18 : R[w,c,t] = sum_o dc_w[w,o] * conv1_w[w*128+o, c, t]
//  bid < 274 : gkT[w][j][c] = gk_w[c][w][j]
//  bid ==274 : fsum[o] = sum_oc fusion_w[o, 512+oc]
//  bid < 851 : A/P: A[w,o,m] = sum_oc fusion_w[o,w*128+oc]*cw[w,oc,m]; P col 512+
//  else      : k1 role (1040 blocks): pad x->bf16 xpad + rowT/colF/colL partials
//    rowT[b][r][j][c] = sum over 64-col half j of row r; colF/colL = x at first/
//    last col of half j. k2 reduces these (coalesced) into the 5 window stats.
// ---------------------------------------------------------------------------
__global__ void kd1(const float* __restrict__ dc_w, const float* __restrict__ conv1_w,
                    const float* __restrict__ gk_w, const float* __restrict__ fusion_w,
                    const float* __restrict__ x,
                    float* __restrict__ R, float* __restrict__ gkT,
                    float* __restrict__ fsum, float* __restrict__ A,
                    float* __restrict__ P, u16* __restrict__ xpad,
                    float* __restrict__ rowT, float* __restrict__ colF,
                    float* __restrict__ colL) {
  const int bid = blockIdx.x, tid = threadIdx.x;
  __shared__ f32x4 ls[8][32];
  if (bid < 18) {
    int gid = bid * 256 + tid;                  // 0..4607
    int w = gid / 1152, m = gid % 1152;
    float s = 0.f;
    for (int o = 0; o < 128; ++o)
      s += dc_w[w * 128 + o] * conv1_w[(size_t)(w * 128 + o) * 1152 + m];
    R[gid] = s;
  } else if (bid < 274) {
    int gid = (bid - 18) * 256 + tid;           // 0..65535
    int w = gid >> 14, j = (gid >> 7) & 127, c = gid & 127;
    gkT[gid] = gk_w[c * 512 + w * 128 + j];
  } else if (bid == 274) {
    if (tid < 128) {
      float s = 0.f;
      for (int oc = 0; oc < 128; ++oc) s += fusion_w[tid * 640 + 512 + oc];
      fsum[tid] = s;
    }
  } else if (bid < 851) {
    int gid = (bid - 275) * 256 + tid;          // 0..147455
    int w = gid / 36864;
    int rem = gid % 36864;
    int o = rem / 288;
    int m = (rem % 288) * 4;
    const float* fw1 = fusion_w + o * 640 + w * 128;
    const float* fw4 = fusion_w + o * 640 + 512;
    const float* cw = conv1_w + (size_t)w * 128 * 1152 + m;
    float a0 = 0, a1 = 0, a2 = 0, a3 = 0, p0 = 0, p1 = 0, p2 = 0, p3 = 0;
    for (int oc = 0; oc < 128; ++oc) {
      float f1 = fw1[oc], f4 = fw4[oc];
      float4 cv = *(const float4*)(cw + (size_t)oc * 1152);
      a0 += f1 * cv.x; a1 += f1 * cv.y; a2 += f1 * cv.z; a3 += f1 * cv.w;
      p0 += f4 * cv.x; p1 += f4 * cv.y; p2 += f4 * cv.z; p3 += f4 * cv.w;
    }
    float4* Ao = (float4*)(A + (size_t)(w * 128 + o) * 1152 + m);
    float4* Po = (float4*)(P + (size_t)(w * 128 + o) * 1152 + m);
    *Ao = make_float4(a0, a1, a2, a3);
    *Po = make_float4(p0, p1, p2, p3);
  } else {
    // ---- k1 role: (rp, b) = padded row, batch ----
    const int kb = bid - 851;                   // 0..1039
    const int rp = kb % 130;
    const int b = kb / 130;
    const size_t xpb = ((size_t)b * 130 + rp) * 16640;
    if (rp == 0 || rp == 129) {
      const bf16x8 z = {0, 0, 0, 0, 0, 0, 0, 0};
      #pragma unroll
      for (int rr = 0; rr < 8; ++rr)
        *(bf16x8*)(xpad + xpb + (size_t)(rr * 256 + tid) * 8) = z;
      if (tid < 32)
        *(bf16x8*)(xpad + xpb + (size_t)(2048 + tid) * 8) = z;
      return;
    }
    const int r = rp - 1;
    if (tid < 32) {
      *(u16x4*)(xpad + xpb + tid * 4) = (u16x4){0, 0, 0, 0};
    } else if (tid < 64) {
      *(u16x4*)(xpad + xpb + 129 * 128 + (tid - 32) * 4) = (u16x4){0, 0, 0, 0};
    }
    const int s = tid >> 5;          // pixel strip 0..7 (16 px each)
    const int cg = tid & 31;         // channel group
    const int c0 = cg * 4;
    const float* xr = x + ((size_t)b * 16384 + (size_t)r * 128) * 128;
    f32x4 sum = {0.f, 0.f, 0.f, 0.f};
    f32x4 cap = {0.f, 0.f, 0.f, 0.f};
    #pragma unroll
    for (int qi = 0; qi < 16; ++qi) {
      const int q = s * 16 + qi;
      f32x4 v = *(const f32x4*)(xr + (size_t)q * 128 + c0);
      sum += v;
      if (qi == 0 && (s == 0 || s == 4)) cap = v;   // q == 0 / 64
      if (qi == 15 && (s == 3 || s == 7)) cap = v;  // q == 63 / 127
      u16x4 st = { f2bf(v[0]), f2bf(v[1]), f2bf(v[2]), f2bf(v[3]) };
      *(u16x4*)(xpad + xpb + (size_t)(q + 1) * 128 + c0) = st;
    }
    const size_t rT2 = ((size_t)b * 128 + r) * 2;
    if (s == 0)      *(f32x4*)(colF + (rT2 + 0) * 128 + c0) = cap;
    else if (s == 4) *(f32x4*)(colF + (rT2 + 1) * 128 + c0) = cap;
    else if (s == 3) *(f32x4*)(colL + (rT2 + 0) * 128 + c0) = cap;
    else if (s == 7) *(f32x4*)(colL + (rT2 + 1) * 128 + c0) = cap;
    ls[s][cg] = sum;
    __syncthreads();
    if (tid < 64) {
      const int h = tid >> 5, g = tid & 31;
      f32x4 T = ls[h * 4 + 0][g] + ls[h * 4 + 1][g] + ls[h * 4 + 2][g] + ls[h * 4 + 3][g];
      *(f32x4*)(rowT + (rT2 + h) * 128 + g * 4) = T;
    }
  }
}

// ---------------------------------------------------------------------------
// K2: per-batch SE gate ww[b][w] from row partials (all reads coalesced,
// L2-resident; replaces both the agg atomic reads and the x-corner scatter).
// ---------------------------------------------------------------------------
__global__ void k2_ww(const float* __restrict__ rowT, const float* __restrict__ colF,
                      const float* __restrict__ colL, const float* __restrict__ R,
                      const float* __restrict__ dc_b,
                      const float* __restrict__ l1_w, const float* __restrict__ l1_b,
                      const float* __restrict__ l2_w, const float* __restrict__ l2_b,
                      float* __restrict__ ww) {
  const int b = blockIdx.x;
  const int tid = threadIdx.x;
  const int w = tid >> 6, lane = tid & 63;
  __shared__ float red[4];
  const int i = w >> 1, j = w & 1;
  float partial = 0.f;
  #pragma unroll
  for (int k = 0; k < 2; ++k) {
    const int c = lane * 2 + k;
    const size_t rbase = ((size_t)b * 128 + i * 64) * 2 + j;
    float T = 0.f, cF = 0.f, cL = 0.f;
    #pragma unroll 4
    for (int ri = 0; ri < 64; ++ri) {
      const size_t idx = (rbase + (size_t)ri * 2) * 128 + c;
      T  += rowT[idx];
      cF += colF[idx];
      cL += colL[idx];
    }
    const size_t i0 = rbase * 128 + c;
    const size_t i63 = (rbase + 126) * 128 + c;
    const float rF = rowT[i0], rL = rowT[i63];
    const float c00 = colF[i0], c0L = colL[i0];
    const float cL0 = colF[i63], cLL = colL[i63];
    float S[9];
    S[0] = T - rL - cL + cLL;
    S[1] = T - rL;
    S[2] = T - rL - cF + cL0;
    S[3] = T - cL;
    S[4] = T;
    S[5] = T - cF;
    S[6] = T - rF - cL + c0L;
    S[7] = T - rF;
    S[8] = T - rF - cF + c00;
    const float* Rp = R + (w * 128 + c) * 9;
    #pragma unroll
    for (int t = 0; t < 9; ++t) partial += S[t] * Rp[t];
  }
  for (int off = 32; off > 0; off >>= 1) partial += __shfl_xor(partial, off, 64);
  if (lane == 0) red[w] = partial;
  __syncthreads();
  if (tid == 0) {
    float ww0[4];
    #pragma unroll
    for (int w2 = 0; w2 < 4; ++w2) ww0[w2] = red[w2] * (1.f / 4096.f) + dc_b[w2];
    float h1[16];
    for (int i2 = 0; i2 < 16; ++i2) {
      float s = l1_b[i2];
      #pragma unroll
      for (int w2 = 0; w2 < 4; ++w2) s += l1_w[i2 * 4 + w2] * ww0[w2];
      h1[i2] = 0.5f * s * (1.f + erff(s * 0.70710678118654752f));
    }
    for (int w2 = 0; w2 < 4; ++w2) {
      float s = l2_b[w2];
      for (int i2 = 0; i2 < 16; ++i2) s += l2_w[w2 * 16 + i2] * h1[i2];
      ww[b * 4 + w2] = 1.f / (1.f + expf(-s));
    }
  }
}

// ---------------------------------------------------------------------------
// K45: fused k4+k5 (proven ~fast): reads precomputed ww.
// keff[b,t,o,c] = f2bf( sum_w ww[b,w]*(A[w,o,c*9+t] + sum_j P[w,o,j*9+t]*gkT[w,j,c])
//                       + fsum[o]*gk_b[c] )
// ---------------------------------------------------------------------------
__global__ void k45_keff(const float* __restrict__ A, const float* __restrict__ P,
                         const float* __restrict__ gkT, const float* __restrict__ ww,
                         const float* __restrict__ fsum, const float* __restrict__ gk_b,
                         u16* __restrict__ keff) {
  const int t = blockIdx.x >> 6;          // 0..8
  const int o0 = (blockIdx.x & 63) * 2;   // o-pair base
  const int tid = threadIdx.x;
  __shared__ float pl[2][4][128];
  __shared__ float al[2][4][128];
  __shared__ float red[2][2][4][128];
  #pragma unroll
  for (int rr = 0; rr < 4; ++rr) {
    const int idx = rr * 256 + tid;       // oi*512 + w*128 + j
    const int oi = idx >> 9, w = (idx >> 7) & 3, j = idx & 127;
    const size_t src = (size_t)(w * 128 + o0 + oi) * 1152 + j * 9 + t;
    pl[oi][w][j] = P[src];
    al[oi][w][j] = A[src];
  }
  __syncthreads();
  const int c = tid & 127, jh = tid >> 7;
  float acc[2][4];
  #pragma unroll
  for (int oi = 0; oi < 2; ++oi)
    #pragma unroll
    for (int w = 0; w < 4; ++w) acc[oi][w] = 0.f;
  const float* g = gkT + c;
  #pragma unroll 4
  for (int j = jh * 64; j < jh * 64 + 64; ++j) {
    const float g0 = g[0 * 16384 + j * 128];
    const float g1 = g[1 * 16384 + j * 128];
    const float g2 = g[2 * 16384 + j * 128];
    const float g3 = g[3 * 16384 + j * 128];
    #pragma unroll
    for (int oi = 0; oi < 2; ++oi) {
      acc[oi][0] += pl[oi][0][j] * g0;
      acc[oi][1] += pl[oi][1][j] * g1;
      acc[oi][2] += pl[oi][2][j] * g2;
      acc[oi][3] += pl[oi][3][j] * g3;
    }
  }
  #pragma unroll
  for (int oi = 0; oi < 2; ++oi)
    #pragma unroll
    for (int w = 0; w < 4; ++w) red[jh][oi][w][c] = acc[oi][w];
  __syncthreads();
  const int oi2 = tid >> 7, c2 = tid & 127;
  float m[4];
  #pragma unroll
  for (int w = 0; w < 4; ++w)
    m[w] = red[0][oi2][w][c2] + red[1][oi2][w][c2] + al[oi2][w][c2];
  const float base = fsum[o0 + oi2] * gk_b[c2];
  #pragma unroll
  for (int b = 0; b < 8; ++b) {
    float r = base;
    #pragma unroll
    for (int w = 0; w < 4; ++w) r += ww[b * 4 + w] * m[w];
    keff[(size_t)b * 147456 + (size_t)t * 16384 + (o0 + oi2) * 128 + c2] = f2bf(r);
  }
}

// ---------------------------------------------------------------------------
// K6: per-batch 3x3 C->C conv as 9 accumulated bf16 MFMA GEMMs.
// Reverted to the round-4 proven ordering (W-write THEN A-DMA).
// ---------------------------------------------------------------------------
__global__ __launch_bounds__(256, 2) void k6_conv(
    const u16* __restrict__ xpad, const u16* __restrict__ keff,
    const float* __restrict__ fusion_b, float* __restrict__ out) {
  __shared__ __align__(16) u16 alds[130 * 128];   // 33,280 B
  __shared__ __align__(16) u16 apad[256];         // 512 B guard for masked DMA tail
  __shared__ __align__(16) u16 wlds[128 * 128];   // 32,768 B
  const int tid = threadIdx.x;
  const int blk = blockIdx.x;
  const int b = blk & 7;            // XCD affinity: batch <-> XCD
  const int p = blk >> 3;
  const int wid = tid >> 6;
  const int lane = tid & 63;
  const int wm = (wid & 1) * 64;
  const int wn = (wid >> 1) * 64;
  const int quad = lane >> 4;
  const int l16 = lane & 15;

  f32x4 acc[4][4];
  #pragma unroll
  for (int i = 0; i < 4; ++i)
    #pragma unroll
    for (int j = 0; j < 4; ++j)
      acc[i][j] = (f32x4){0.f, 0.f, 0.f, 0.f};

  const u16* kb = keff + (size_t)b * 147456;
  const u16* xb = xpad + (size_t)b * 130 * 16640;
  bf16x8 streg[8];
  (void)apad;

  auto stage_W_load = [&](int tap) {
    const u16* src = kb + tap * 16384;
    #pragma unroll
    for (int it = 0; it < 8; ++it) {
      const int chunk = it * 256 + tid;
      const int gs = chunk ^ ((chunk >> 4) & 7);
      streg[it] = *(const bf16x8*)(src + gs * 8);
    }
  };
  auto stage_W_write = [&]() {
    #pragma unroll
    for (int it = 0; it < 8; ++it)
      *(bf16x8*)(wlds + (it * 256 + tid) * 8) = streg[it];
  };
  auto stage_A_dma = [&](int prow) {
    const u16* src = xb + (size_t)prow * 16640;
    #pragma unroll
    for (int r = 0; r < 8; ++r) {
      const int chunk = (wid * 8 + r) * 64 + lane;
      const int gs = chunk ^ ((chunk >> 4) & 7);
      __builtin_amdgcn_global_load_lds(
          (const __attribute__((address_space(1))) unsigned int*)(src + (size_t)gs * 8),
          (__attribute__((address_space(3))) unsigned int*)(alds + (wid * 8 + r) * 512),
          16, 0, 0);
    }
    if (tid < 32) {
      const int chunk = 2048 + tid;
      const int gs = chunk ^ ((chunk >> 4) & 7);
      __builtin_amdgcn_global_load_lds(
          (const __attribute__((address_space(1))) unsigned int*)(src + (size_t)gs * 8),
          (__attribute__((address_space(3))) unsigned int*)(alds + 2048 * 8),
          16, 0, 0);
    }
  };

  stage_W_load(0);
  stage_A_dma(p);
  stage_W_write();
  __syncthreads();   // drains vmcnt -> DMA complete, W visible

  for (int tap = 0; tap < 9; ++tap) {
    if (tap < 8) stage_W_load(tap + 1);         // global->reg, overlaps MFMA
    const int dw = tap % 3 - 1;
    const int pixoff = 1 + dw;
    #pragma unroll
    for (int kc = 0; kc < 4; ++kc) {
      const int c0 = kc * 32 + quad * 8;
      bf16x8 a[4], bb[4];
      #pragma unroll
      for (int i = 0; i < 4; ++i) {
        const int pix = pixoff + wm + i * 16 + l16;
        const int off = (pix * 128 + c0) ^ ((pix & 7) << 3);
        a[i] = *(const bf16x8*)(alds + off);
      }
      #pragma unroll
      for (int j = 0; j < 4; ++j) {
        const int row = wn + j * 16 + l16;
        const int off = (row * 128 + c0) ^ ((row & 7) << 3);
        bb[j] = *(const bf16x8*)(wlds + off);
      }
      #pragma unroll
      for (int i = 0; i < 4; ++i)
        #pragma unroll
        for (int j = 0; j < 4; ++j)
          acc[i][j] = __builtin_amdgcn_mfma_f32_16x16x32_bf16(a[i], bb[j], acc[i][j], 0, 0, 0);
    }
    __syncthreads();                            // all waves done reading alds/wlds
    if (tap < 8) {
      stage_W_write();                          // vmcnt waits streg, then ds_write
      if (tap % 3 == 2) stage_A_dma(p + (tap + 1) / 3);  // next dh row
      __syncthreads();                          // drains vmcnt -> DMA + writes visible
    }
  }

  float fb[4];
  #pragma unroll
  for (int j = 0; j < 4; ++j) fb[j] = fusion_b[wn + j * 16 + l16];
  float* outb = out + ((size_t)b * 16384 + (size_t)p * 128) * 128;
  #pragma unroll
  for (int i = 0; i < 4; ++i)
    #pragma unroll
    for (int r = 0; r < 4; ++r) {
      const int m = wm + i * 16 + quad * 4 + r;
      #pragma unroll
      for (int j = 0; j < 4; ++j)
        outb[(size_t)m * 128 + (wn + j * 16 + l16)] = acc[i][j][r] + fb[j];
    }
}

extern "C" void kernel_launch(void* const* d_in, const int* in_sizes, int n_in,
                              void* d_out, int out_size, void* d_ws, size_t ws_size,
                              hipStream_t stream) {
  const float* x        = (const float*)d_in[0];
  const float* conv1_w  = (const float*)d_in[1];
  const float* dc_w     = (const float*)d_in[2];
  const float* dc_b     = (const float*)d_in[3];
  const float* l1_w     = (const float*)d_in[4];
  const float* l1_b     = (const float*)d_in[5];
  const float* l2_w     = (const float*)d_in[6];
  const float* l2_b     = (const float*)d_in[7];
  const float* gk_w     = (const float*)d_in[8];
  const float* gk_b     = (const float*)d_in[9];
  const float* fusion_w = (const float*)d_in[10];
  const float* fusion_b = (const float*)d_in[11];
  float* out = (float*)d_out;
  char* ws = (char*)d_ws;

  float* wwp  = (float*)(ws + OFF_WW);
  float* R    = (float*)(ws + OFF_R);
  float* fsum = (float*)(ws + OFF_FSUM);
  float* gkT  = (float*)(ws + OFF_GKT);
  float* A    = (float*)(ws + OFF_A);
  float* P    = (float*)(ws + OFF_P);
  float* rowT = (float*)(ws + OFF_M);
  float* colF = (float*)(ws + OFF_M + 1048576u);
  float* colL = (float*)(ws + OFF_KEFF);        // overlays keff; consumed by k2 before k45 writes
  u16* keff   = (u16*)(ws + OFF_KEFF);
  u16* xpad   = (u16*)(ws + OFF_XPAD);

  // 4 dispatches: {weights + x-side} prep, tiny ww, keff, conv.
  kd1<<<1891, 256, 0, stream>>>(dc_w, conv1_w, gk_w, fusion_w, x,
                                R, gkT, fsum, A, P, xpad, rowT, colF, colL);
  k2_ww<<<8, 256, 0, stream>>>(rowT, colF, colL, R, dc_b, l1_w, l1_b, l2_w, l2_b, wwp);
  k45_keff<<<576, 256, 0, stream>>>(A, P, gkT, wwp, fsum, gk_b, keff);
  k6_conv<<<1024, 256, 0, stream>>>(xpad, keff, fusion_b, out);
}